// Round 8
// baseline (873.831 us; speedup 1.0000x reference)
//
#include <hip/hip_runtime.h>

// h <- A_norm h, 12 times, in u-space (u = rsqrt(deg).*h):
//   u'[d] = (1/deg[d]) * (u[d] + sum_{s in N(d)} u[s]),  h12 = sqrt(deg).*u12
// CSR built per call (bucketed, atomic-light). Layers run as TWO half-feature
// passes (uA,uB = [n][8] f32 = 3.2MB each) so the gather table fits the 4MB
// per-XCD L2 -> no capacity misses (R7: u=6.4MB gave 112MB/layer L2-miss
// traffic at 2.8TB/s = the bottleneck). adj is nontemporal (stream, no reuse).
// Isolated nodes zeroed at the END (they never propagate -> equivalent).

#define NB 256
#define SBSHIFT 8
#define SBSIZE 256
#define NSBP 512          // padded bin count (nsb = ceil(n/256) = 391 <= 512)
#define CH 4096           // edges per reorder chunk
#define RT 512            // reorder threads
#define EPT 8             // CH / RT

typedef int   v4i __attribute__((ext_vector_type(4)));
typedef float v4f __attribute__((ext_vector_type(4)));

__global__ void k_zero(int* __restrict__ sbhist, unsigned* __restrict__ mask, int nsb, int nm) {
    int i = blockIdx.x * NB + threadIdx.x;
    if (i < nsb) sbhist[i] = 0;
    if (i < nm) mask[i] = 0u;
}

__global__ void k_hist(const int* __restrict__ dst, int e, int* __restrict__ sbhist, int nsb) {
    __shared__ int lh[NSBP];
    for (int b = threadIdx.x; b < NSBP; b += NB) lh[b] = 0;
    __syncthreads();
    int stride = gridDim.x * NB;
    for (int i = blockIdx.x * NB + threadIdx.x; i < e; i += stride)
        atomicAdd(&lh[dst[i] >> SBSHIFT], 1);
    __syncthreads();
    for (int b = threadIdx.x; b < nsb; b += NB)
        if (lh[b]) atomicAdd(&sbhist[b], lh[b]);
}

__global__ __launch_bounds__(NSBP) void k_scan_sb(const int* __restrict__ sbhist,
                                                  int* __restrict__ sbbase,
                                                  int* __restrict__ bcur, int nsb) {
    __shared__ int sh[NSBP];
    int t = threadIdx.x;
    int v = (t < nsb) ? sbhist[t] : 0;
    sh[t] = v;
    __syncthreads();
    for (int off = 1; off < NSBP; off <<= 1) {
        int add = (t >= off) ? sh[t - off] : 0;
        __syncthreads();
        sh[t] += add;
        __syncthreads();
    }
    int incl = sh[t];
    if (t < nsb) { sbbase[t] = incl - v; bcur[t] = incl - v; }
    if (t == nsb - 1) sbbase[nsb] = incl;
}

// chunk-staged reorder: sedge[pos] = (src<<8)|(dst&255), bucket-sorted
__global__ __launch_bounds__(RT) void k_reorder(const int* __restrict__ src,
                                                const int* __restrict__ dst, int e,
                                                int* __restrict__ bcur, int* __restrict__ sedge) {
    __shared__ int lsize[NSBP];
    __shared__ int lscan[NSBP];
    __shared__ int ldelta[NSBP];
    __shared__ int lcur[NSBP];
    __shared__ int stage[CH];
    __shared__ int gpos[CH];
    int t = threadIdx.x;
    int base = blockIdx.x * CH;
    int cnt_here = e - base; if (cnt_here > CH) cnt_here = CH;
    lsize[t] = 0;
    __syncthreads();
    int myb[EPT], myw[EPT];
#pragma unroll
    for (int k = 0; k < EPT; ++k) {
        int i = base + k * RT + t;
        if (i < e) {
            int s = src[i], d = dst[i];
            int b = d >> SBSHIFT;
            myb[k] = b;
            myw[k] = (s << SBSHIFT) | (d & (SBSIZE - 1));
            atomicAdd(&lsize[b], 1);
        } else myb[k] = -1;
    }
    __syncthreads();
    int v = lsize[t];
    lscan[t] = v;
    __syncthreads();
    for (int off = 1; off < NSBP; off <<= 1) {
        int add = (t >= off) ? lscan[t - off] : 0;
        __syncthreads();
        lscan[t] += add;
        __syncthreads();
    }
    int excl = lscan[t] - v;
    if (v > 0) ldelta[t] = atomicAdd(&bcur[t], v) - excl;
    lcur[t] = excl;
    __syncthreads();
#pragma unroll
    for (int k = 0; k < EPT; ++k) {
        int b = myb[k];
        if (b >= 0) {
            int sl = atomicAdd(&lcur[b], 1);
            stage[sl] = myw[k];
            gpos[sl] = ldelta[b] + sl;
        }
    }
    __syncthreads();
    for (int s2 = t; s2 < cnt_here; s2 += RT)
        sedge[gpos[s2]] = stage[s2];
}

__global__ __launch_bounds__(SBSIZE) void k_fine_cnt(const int* __restrict__ sedge,
                                                     const int* __restrict__ sbbase,
                                                     int* __restrict__ cnt, int n) {
    __shared__ int lc[SBSIZE];
    int t = threadIdx.x;
    lc[t] = 0;
    __syncthreads();
    int lo = sbbase[blockIdx.x], hi = sbbase[blockIdx.x + 1];
    for (int i = lo + t; i < hi; i += SBSIZE)
        atomicAdd(&lc[sedge[i] & (SBSIZE - 1)], 1);
    __syncthreads();
    int node = (blockIdx.x << SBSHIFT) + t;
    if (node < n) cnt[node] = lc[t];
}

// ---- exclusive scan of padded counts ((cnt+3)&~3) -> rowptr ----
__global__ void k_scan1(const int* __restrict__ cnt, int* __restrict__ partial, int n) {
    __shared__ int sd[NB];
    int i = blockIdx.x * NB + threadIdx.x;
    sd[threadIdx.x] = (i < n) ? ((cnt[i] + 3) & ~3) : 0;
    __syncthreads();
    for (int s = NB / 2; s > 0; s >>= 1) {
        if (threadIdx.x < s) sd[threadIdx.x] += sd[threadIdx.x + s];
        __syncthreads();
    }
    if (threadIdx.x == 0) partial[blockIdx.x] = sd[0];
}

__global__ void k_scan2(int* __restrict__ partial, int nb) {
    __shared__ int sd[512];
    int t = threadIdx.x;
    int v = (t < nb) ? partial[t] : 0;
    sd[t] = v;
    __syncthreads();
    for (int off = 1; off < 512; off <<= 1) {
        int add = (t >= off) ? sd[t - off] : 0;
        __syncthreads();
        sd[t] += add;
        __syncthreads();
    }
    if (t < nb) partial[t] = sd[t] - v;   // exclusive
}

__global__ void k_scan3(const int* __restrict__ cnt, const int* __restrict__ partial,
                        int* __restrict__ rowptr, int n) {
    __shared__ int sd[NB];
    int i = blockIdx.x * NB + threadIdx.x;
    int v = (i < n) ? ((cnt[i] + 3) & ~3) : 0;
    sd[threadIdx.x] = v;
    __syncthreads();
    for (int off = 1; off < NB; off <<= 1) {
        int add = (threadIdx.x >= off) ? sd[threadIdx.x - off] : 0;
        __syncthreads();
        sd[threadIdx.x] += add;
        __syncthreads();
    }
    int ex = sd[threadIdx.x] - v + partial[blockIdx.x];
    if (i < n) rowptr[i] = ex;
    if (i == n - 1) rowptr[n] = ex + v;
}

// per-bucket place via LDS cursors; pad slots filled in epilogue
__global__ __launch_bounds__(SBSIZE) void k_place(const int* __restrict__ sedge,
                                                  const int* __restrict__ sbbase,
                                                  const int* __restrict__ rowptr,
                                                  const int* __restrict__ cnt,
                                                  unsigned* __restrict__ mask,
                                                  int* __restrict__ adj, int n) {
    __shared__ int lcur[SBSIZE];
    int t = threadIdx.x;
    int node = (blockIdx.x << SBSHIFT) + t;
    lcur[t] = (node < n) ? rowptr[node] : 0;
    __syncthreads();
    int lo = sbbase[blockIdx.x], hi = sbbase[blockIdx.x + 1];
    for (int i = lo + t; i < hi; i += SBSIZE) {
        int w = sedge[i];
        int d = w & (SBSIZE - 1);
        int s = w >> SBSHIFT;
        int pos = atomicAdd(&lcur[d], 1);
        adj[pos] = s;
        if (cnt[s] == 0) atomicOr(&mask[s >> 5], 1u << (s & 31));  // rare
    }
    __syncthreads();
    if (node < n) {
        int en = rowptr[node + 1];
        for (int p = lcur[t]; p < en; ++p) adj[p] = node;  // lcur[t]==rowptr+cnt
    }
}

// u0 = x * rsqrt(deg), split into uA (feats 0..7) / uB (feats 8..15)
__global__ void k_init_u(const v4f* __restrict__ x, const int* __restrict__ cnt,
                         v4f* __restrict__ uA, v4f* __restrict__ uB, int n4) {
    int i = blockIdx.x * NB + threadIdx.x;
    if (i >= n4) return;
    int node = i >> 2, q = i & 3;
    float is = rsqrtf((float)(cnt[node] + 1));
    v4f v = x[i] * is;
    (q < 2 ? uA : uB)[(size_t)node * 2 + (q & 1)] = v;
}

// half-feature layer: 2 threads per node, u table = [n][8] f32 (3.2MB, L2-fits)
__global__ void k_layer_half(const int* __restrict__ rowptr, const int* __restrict__ cnt,
                             const int* __restrict__ adj,
                             const v4f* __restrict__ u, v4f* __restrict__ un, int n) {
    int t = blockIdx.x * NB + threadIdx.x;
    int node = t >> 1, hq = t & 1;
    if (node >= n) return;
    int beg = rowptr[node], endp = rowptr[node + 1];
    int deg = cnt[node];
    float corr = (float)(1 - (endp - beg - deg));   // 1 - pads
    float c0 = 1.0f / (float)(deg + 1);
    v4f self = u[(size_t)node * 2 + hq];
    v4f accA = (v4f)(0.0f);
    v4f accB = (v4f)(0.0f);
    int p = beg;
    for (; p + 8 <= endp; p += 8) {
        v4i sa = __builtin_nontemporal_load((const v4i*)(adj + p));
        v4i sb = __builtin_nontemporal_load((const v4i*)(adj + p + 4));
        v4f v0 = u[(size_t)sa.x * 2 + hq];
        v4f v1 = u[(size_t)sa.y * 2 + hq];
        v4f v2 = u[(size_t)sa.z * 2 + hq];
        v4f v3 = u[(size_t)sa.w * 2 + hq];
        v4f w0 = u[(size_t)sb.x * 2 + hq];
        v4f w1 = u[(size_t)sb.y * 2 + hq];
        v4f w2 = u[(size_t)sb.z * 2 + hq];
        v4f w3 = u[(size_t)sb.w * 2 + hq];
        accA += (v0 + v1) + (v2 + v3);
        accB += (w0 + w1) + (w2 + w3);
    }
    if (p < endp) {
        v4i sa = __builtin_nontemporal_load((const v4i*)(adj + p));
        v4f v0 = u[(size_t)sa.x * 2 + hq];
        v4f v1 = u[(size_t)sa.y * 2 + hq];
        v4f v2 = u[(size_t)sa.z * 2 + hq];
        v4f v3 = u[(size_t)sa.w * 2 + hq];
        accA += (v0 + v1) + (v2 + v3);
    }
    v4f r = (accA + accB + corr * self) * c0;
    __builtin_nontemporal_store(r, un + (size_t)node * 2 + hq);
}

// h12 = sqrt(deg).*u12 re-interleaved into d_out, zero if isolated
__global__ void k_finish(const v4f* __restrict__ uA, const v4f* __restrict__ uB,
                         v4f* __restrict__ h, const int* __restrict__ cnt,
                         const unsigned* __restrict__ mask, int n4) {
    int i = blockIdx.x * NB + threadIdx.x;
    if (i >= n4) return;
    int node = i >> 2, q = i & 3;
    int c = cnt[node];
    bool nonisol = (c > 0) || (((mask[node >> 5] >> (node & 31)) & 1u) != 0u);
    float s = nonisol ? sqrtf((float)(c + 1)) : 0.0f;
    v4f v = (q < 2 ? uA : uB)[(size_t)node * 2 + (q & 1)];
    h[i] = v * s;
}

extern "C" void kernel_launch(void* const* d_in, const int* in_sizes, int n_in,
                              void* d_out, int out_size, void* d_ws, size_t ws_size,
                              hipStream_t stream) {
    const float* x  = (const float*)d_in[0];
    const int*   ei = (const int*)d_in[1];
    const int n = in_sizes[0] / 16;   // 100000
    const int e = in_sizes[1] / 2;    // 3200000
    const int* src = ei;
    const int* dst = ei + e;
    const int nm  = (n + 31) / 32;
    const int nsb = (n + SBSIZE - 1) >> SBSHIFT;   // 391

    char* ws = (char*)d_ws;
    auto take = [&](size_t bytes) {
        char* p = ws;
        ws += (bytes + 255) & ~(size_t)255;
        return p;
    };
    int*      sbhist  = (int*)take((size_t)NSBP * sizeof(int));
    int*      sbbase  = (int*)take((size_t)(NSBP + 1) * sizeof(int));
    int*      bcur    = (int*)take((size_t)NSBP * sizeof(int));
    unsigned* mask    = (unsigned*)take((size_t)nm * sizeof(unsigned));
    int*      cnt     = (int*)take((size_t)n * sizeof(int));
    int*      rowptr  = (int*)take((size_t)(n + 1) * sizeof(int));
    int*      partial = (int*)take(512 * sizeof(int));
    int*      sedge   = (int*)take((size_t)e * sizeof(int));
    int*      adj     = (int*)take((size_t)(e + 4 * n) * sizeof(int));
    v4f*      WA      = (v4f*)take((size_t)n * 8 * sizeof(float));  // [n][8]
    v4f*      WB      = (v4f*)take((size_t)n * 8 * sizeof(float));  // [n][8]
    // d_out doubles as the ping-pong partner: [uA half | uB half]
    v4f*      DA      = (v4f*)d_out;
    v4f*      DB      = DA + (size_t)n * 2;

    const int gn  = (n + NB - 1) / NB;       // 391
    const int gn4 = (n * 4 + NB - 1) / NB;   // 1563
    const int gh  = (n * 2 + NB - 1) / NB;   // 782
    const int gre = (e + CH - 1) / CH;       // 782
    const int gz  = (((nsb > nm) ? nsb : nm) + NB - 1) / NB;

    k_zero<<<gz, NB, 0, stream>>>(sbhist, mask, nsb, nm);
    k_hist<<<512, NB, 0, stream>>>(dst, e, sbhist, nsb);
    k_scan_sb<<<1, NSBP, 0, stream>>>(sbhist, sbbase, bcur, nsb);
    k_reorder<<<gre, RT, 0, stream>>>(src, dst, e, bcur, sedge);
    k_fine_cnt<<<nsb, SBSIZE, 0, stream>>>(sedge, sbbase, cnt, n);
    k_scan1<<<gn, NB, 0, stream>>>(cnt, partial, n);
    k_scan2<<<1, 512, 0, stream>>>(partial, gn);
    k_scan3<<<gn, NB, 0, stream>>>(cnt, partial, rowptr, n);
    k_place<<<nsb, SBSIZE, 0, stream>>>(sedge, sbbase, rowptr, cnt, mask, adj, n);
    k_init_u<<<gn4, NB, 0, stream>>>((const v4f*)x, cnt, WA, WB, n * 4);

    // 12 layers, each = two independent half-feature passes.
    // u0 in W; even layer count -> final u in W; k_finish writes d_out.
    v4f *curA = WA, *curB = WB, *nxtA = DA, *nxtB = DB;
    for (int l = 0; l < 12; ++l) {
        k_layer_half<<<gh, NB, 0, stream>>>(rowptr, cnt, adj, curA, nxtA, n);
        k_layer_half<<<gh, NB, 0, stream>>>(rowptr, cnt, adj, curB, nxtB, n);
        v4f* tp;
        tp = curA; curA = nxtA; nxtA = tp;
        tp = curB; curB = nxtB; nxtB = tp;
    }
    k_finish<<<gn4, NB, 0, stream>>>(curA, curB, (v4f*)d_out, cnt, mask, n * 4);
}

// Round 9
// 604.394 us; speedup vs baseline: 1.4458x; 1.4458x over previous
//
#include <hip/hip_runtime.h>

// h <- A_norm h, 12 times, in u-space (u = rsqrt(deg).*h):
//   u'[d] = (1/deg[d]) * (u[d] + sum_{s in N(d)} u[s]),  h12 = sqrt(deg).*u12
// CSR built per call (bucketed, atomic-light). Layer kernel: full-width
// (4 lanes/node, 64B line per gather fully used), adj via nontemporal load
// (stream; don't pollute L2), NORMAL un store (next layer reads it), and
// 16 gathers in flight per thread to cover ~200cy L2/LLC miss latency.
// Isolated nodes zeroed at the END (they never propagate -> equivalent).

#define NB 256
#define SBSHIFT 8
#define SBSIZE 256
#define NSBP 512          // padded bin count (nsb = ceil(n/256) = 391 <= 512)
#define CH 4096           // edges per reorder chunk
#define RT 512            // reorder threads
#define EPT 8             // CH / RT

typedef int   v4i __attribute__((ext_vector_type(4)));
typedef float v4f __attribute__((ext_vector_type(4)));

__global__ void k_zero(int* __restrict__ sbhist, unsigned* __restrict__ mask, int nsb, int nm) {
    int i = blockIdx.x * NB + threadIdx.x;
    if (i < nsb) sbhist[i] = 0;
    if (i < nm) mask[i] = 0u;
}

__global__ void k_hist(const int* __restrict__ dst, int e, int* __restrict__ sbhist, int nsb) {
    __shared__ int lh[NSBP];
    for (int b = threadIdx.x; b < NSBP; b += NB) lh[b] = 0;
    __syncthreads();
    int stride = gridDim.x * NB;
    for (int i = blockIdx.x * NB + threadIdx.x; i < e; i += stride)
        atomicAdd(&lh[dst[i] >> SBSHIFT], 1);
    __syncthreads();
    for (int b = threadIdx.x; b < nsb; b += NB)
        if (lh[b]) atomicAdd(&sbhist[b], lh[b]);
}

__global__ __launch_bounds__(NSBP) void k_scan_sb(const int* __restrict__ sbhist,
                                                  int* __restrict__ sbbase,
                                                  int* __restrict__ bcur, int nsb) {
    __shared__ int sh[NSBP];
    int t = threadIdx.x;
    int v = (t < nsb) ? sbhist[t] : 0;
    sh[t] = v;
    __syncthreads();
    for (int off = 1; off < NSBP; off <<= 1) {
        int add = (t >= off) ? sh[t - off] : 0;
        __syncthreads();
        sh[t] += add;
        __syncthreads();
    }
    int incl = sh[t];
    if (t < nsb) { sbbase[t] = incl - v; bcur[t] = incl - v; }
    if (t == nsb - 1) sbbase[nsb] = incl;
}

// chunk-staged reorder: sedge[pos] = (src<<8)|(dst&255), bucket-sorted
__global__ __launch_bounds__(RT) void k_reorder(const int* __restrict__ src,
                                                const int* __restrict__ dst, int e,
                                                int* __restrict__ bcur, int* __restrict__ sedge) {
    __shared__ int lsize[NSBP];
    __shared__ int lscan[NSBP];
    __shared__ int ldelta[NSBP];
    __shared__ int lcur[NSBP];
    __shared__ int stage[CH];
    __shared__ int gpos[CH];
    int t = threadIdx.x;
    int base = blockIdx.x * CH;
    int cnt_here = e - base; if (cnt_here > CH) cnt_here = CH;
    lsize[t] = 0;
    __syncthreads();
    int myb[EPT], myw[EPT];
#pragma unroll
    for (int k = 0; k < EPT; ++k) {
        int i = base + k * RT + t;
        if (i < e) {
            int s = src[i], d = dst[i];
            int b = d >> SBSHIFT;
            myb[k] = b;
            myw[k] = (s << SBSHIFT) | (d & (SBSIZE - 1));
            atomicAdd(&lsize[b], 1);
        } else myb[k] = -1;
    }
    __syncthreads();
    int v = lsize[t];
    lscan[t] = v;
    __syncthreads();
    for (int off = 1; off < NSBP; off <<= 1) {
        int add = (t >= off) ? lscan[t - off] : 0;
        __syncthreads();
        lscan[t] += add;
        __syncthreads();
    }
    int excl = lscan[t] - v;
    if (v > 0) ldelta[t] = atomicAdd(&bcur[t], v) - excl;
    lcur[t] = excl;
    __syncthreads();
#pragma unroll
    for (int k = 0; k < EPT; ++k) {
        int b = myb[k];
        if (b >= 0) {
            int sl = atomicAdd(&lcur[b], 1);
            stage[sl] = myw[k];
            gpos[sl] = ldelta[b] + sl;
        }
    }
    __syncthreads();
    for (int s2 = t; s2 < cnt_here; s2 += RT)
        sedge[gpos[s2]] = stage[s2];
}

__global__ __launch_bounds__(SBSIZE) void k_fine_cnt(const int* __restrict__ sedge,
                                                     const int* __restrict__ sbbase,
                                                     int* __restrict__ cnt, int n) {
    __shared__ int lc[SBSIZE];
    int t = threadIdx.x;
    lc[t] = 0;
    __syncthreads();
    int lo = sbbase[blockIdx.x], hi = sbbase[blockIdx.x + 1];
    for (int i = lo + t; i < hi; i += SBSIZE)
        atomicAdd(&lc[sedge[i] & (SBSIZE - 1)], 1);
    __syncthreads();
    int node = (blockIdx.x << SBSHIFT) + t;
    if (node < n) cnt[node] = lc[t];
}

// ---- exclusive scan of padded counts ((cnt+3)&~3) -> rowptr ----
__global__ void k_scan1(const int* __restrict__ cnt, int* __restrict__ partial, int n) {
    __shared__ int sd[NB];
    int i = blockIdx.x * NB + threadIdx.x;
    sd[threadIdx.x] = (i < n) ? ((cnt[i] + 3) & ~3) : 0;
    __syncthreads();
    for (int s = NB / 2; s > 0; s >>= 1) {
        if (threadIdx.x < s) sd[threadIdx.x] += sd[threadIdx.x + s];
        __syncthreads();
    }
    if (threadIdx.x == 0) partial[blockIdx.x] = sd[0];
}

__global__ void k_scan2(int* __restrict__ partial, int nb) {
    __shared__ int sd[512];
    int t = threadIdx.x;
    int v = (t < nb) ? partial[t] : 0;
    sd[t] = v;
    __syncthreads();
    for (int off = 1; off < 512; off <<= 1) {
        int add = (t >= off) ? sd[t - off] : 0;
        __syncthreads();
        sd[t] += add;
        __syncthreads();
    }
    if (t < nb) partial[t] = sd[t] - v;   // exclusive
}

__global__ void k_scan3(const int* __restrict__ cnt, const int* __restrict__ partial,
                        int* __restrict__ rowptr, int n) {
    __shared__ int sd[NB];
    int i = blockIdx.x * NB + threadIdx.x;
    int v = (i < n) ? ((cnt[i] + 3) & ~3) : 0;
    sd[threadIdx.x] = v;
    __syncthreads();
    for (int off = 1; off < NB; off <<= 1) {
        int add = (threadIdx.x >= off) ? sd[threadIdx.x - off] : 0;
        __syncthreads();
        sd[threadIdx.x] += add;
        __syncthreads();
    }
    int ex = sd[threadIdx.x] - v + partial[blockIdx.x];
    if (i < n) rowptr[i] = ex;
    if (i == n - 1) rowptr[n] = ex + v;
}

// per-bucket place via LDS cursors; pad slots filled in epilogue
__global__ __launch_bounds__(SBSIZE) void k_place(const int* __restrict__ sedge,
                                                  const int* __restrict__ sbbase,
                                                  const int* __restrict__ rowptr,
                                                  const int* __restrict__ cnt,
                                                  unsigned* __restrict__ mask,
                                                  int* __restrict__ adj, int n) {
    __shared__ int lcur[SBSIZE];
    int t = threadIdx.x;
    int node = (blockIdx.x << SBSHIFT) + t;
    lcur[t] = (node < n) ? rowptr[node] : 0;
    __syncthreads();
    int lo = sbbase[blockIdx.x], hi = sbbase[blockIdx.x + 1];
    for (int i = lo + t; i < hi; i += SBSIZE) {
        int w = sedge[i];
        int d = w & (SBSIZE - 1);
        int s = w >> SBSHIFT;
        int pos = atomicAdd(&lcur[d], 1);
        adj[pos] = s;
        if (cnt[s] == 0) atomicOr(&mask[s >> 5], 1u << (s & 31));  // rare
    }
    __syncthreads();
    if (node < n) {
        int en = rowptr[node + 1];
        for (int p = lcur[t]; p < en; ++p) adj[p] = node;  // lcur[t]==rowptr+cnt
    }
}

// u0 = x * rsqrt(deg) (no masking here; isolated zeroed in k_finish)
__global__ void k_init_u(const v4f* __restrict__ x, const int* __restrict__ cnt,
                         v4f* __restrict__ u, int n4) {
    int i = blockIdx.x * NB + threadIdx.x;
    if (i >= n4) return;
    int node = i >> 2;
    float is = rsqrtf((float)(cnt[node] + 1));
    u[i] = x[i] * is;
}

// 4 threads per node; lane q owns float4 quadrant q. 16 gathers in flight.
__global__ __launch_bounds__(NB) void k_layer(const int* __restrict__ rowptr,
                                              const int* __restrict__ cnt,
                                              const int* __restrict__ adj,
                                              const v4f* __restrict__ u,
                                              v4f* __restrict__ un, int n) {
    int t = blockIdx.x * NB + threadIdx.x;
    int node = t >> 2, q = t & 3;
    if (node >= n) return;
    int beg = rowptr[node], endp = rowptr[node + 1];
    int deg = cnt[node];
    float corr = (float)(1 - (endp - beg - deg));   // 1 - pads
    float c0 = 1.0f / (float)(deg + 1);
    v4f self = u[(size_t)node * 4 + q];
    v4f a0 = (v4f)(0.0f), a1 = (v4f)(0.0f), a2 = (v4f)(0.0f), a3 = (v4f)(0.0f);
    int p = beg;
    for (; p + 16 <= endp; p += 16) {
        v4i s0 = __builtin_nontemporal_load((const v4i*)(adj + p));
        v4i s1 = __builtin_nontemporal_load((const v4i*)(adj + p + 4));
        v4i s2 = __builtin_nontemporal_load((const v4i*)(adj + p + 8));
        v4i s3 = __builtin_nontemporal_load((const v4i*)(adj + p + 12));
        v4f g00 = u[(size_t)s0.x * 4 + q];
        v4f g01 = u[(size_t)s0.y * 4 + q];
        v4f g02 = u[(size_t)s0.z * 4 + q];
        v4f g03 = u[(size_t)s0.w * 4 + q];
        v4f g10 = u[(size_t)s1.x * 4 + q];
        v4f g11 = u[(size_t)s1.y * 4 + q];
        v4f g12 = u[(size_t)s1.z * 4 + q];
        v4f g13 = u[(size_t)s1.w * 4 + q];
        v4f g20 = u[(size_t)s2.x * 4 + q];
        v4f g21 = u[(size_t)s2.y * 4 + q];
        v4f g22 = u[(size_t)s2.z * 4 + q];
        v4f g23 = u[(size_t)s2.w * 4 + q];
        v4f g30 = u[(size_t)s3.x * 4 + q];
        v4f g31 = u[(size_t)s3.y * 4 + q];
        v4f g32 = u[(size_t)s3.z * 4 + q];
        v4f g33 = u[(size_t)s3.w * 4 + q];
        a0 += (g00 + g01) + (g02 + g03);
        a1 += (g10 + g11) + (g12 + g13);
        a2 += (g20 + g21) + (g22 + g23);
        a3 += (g30 + g31) + (g32 + g33);
    }
    for (; p + 4 <= endp; p += 4) {
        v4i s0 = __builtin_nontemporal_load((const v4i*)(adj + p));
        v4f g00 = u[(size_t)s0.x * 4 + q];
        v4f g01 = u[(size_t)s0.y * 4 + q];
        v4f g02 = u[(size_t)s0.z * 4 + q];
        v4f g03 = u[(size_t)s0.w * 4 + q];
        a0 += (g00 + g01) + (g02 + g03);
    }
    v4f r = ((a0 + a1) + (a2 + a3) + corr * self) * c0;
    un[(size_t)node * 4 + q] = r;   // normal store: next layer reads this
}

// h12 = sqrt(deg).*u12, zero if isolated (cnt==0 and never seen as src)
__global__ void k_finish(v4f* __restrict__ h, const int* __restrict__ cnt,
                         const unsigned* __restrict__ mask, int n4) {
    int i = blockIdx.x * NB + threadIdx.x;
    if (i >= n4) return;
    int node = i >> 2;
    int c = cnt[node];
    bool nonisol = (c > 0) || (((mask[node >> 5] >> (node & 31)) & 1u) != 0u);
    float s = nonisol ? sqrtf((float)(c + 1)) : 0.0f;
    h[i] = h[i] * s;
}

extern "C" void kernel_launch(void* const* d_in, const int* in_sizes, int n_in,
                              void* d_out, int out_size, void* d_ws, size_t ws_size,
                              hipStream_t stream) {
    const float* x  = (const float*)d_in[0];
    const int*   ei = (const int*)d_in[1];
    const int n = in_sizes[0] / 16;   // 100000
    const int e = in_sizes[1] / 2;    // 3200000
    const int* src = ei;
    const int* dst = ei + e;
    const int nm  = (n + 31) / 32;
    const int nsb = (n + SBSIZE - 1) >> SBSHIFT;   // 391

    char* ws = (char*)d_ws;
    auto take = [&](size_t bytes) {
        char* p = ws;
        ws += (bytes + 255) & ~(size_t)255;
        return p;
    };
    int*      sbhist  = (int*)take((size_t)NSBP * sizeof(int));
    int*      sbbase  = (int*)take((size_t)(NSBP + 1) * sizeof(int));
    int*      bcur    = (int*)take((size_t)NSBP * sizeof(int));
    unsigned* mask    = (unsigned*)take((size_t)nm * sizeof(unsigned));
    int*      cnt     = (int*)take((size_t)n * sizeof(int));
    int*      rowptr  = (int*)take((size_t)(n + 1) * sizeof(int));
    int*      partial = (int*)take(512 * sizeof(int));
    int*      sedge   = (int*)take((size_t)e * sizeof(int));
    int*      adj     = (int*)take((size_t)(e + 4 * n) * sizeof(int));
    float*    uws     = (float*)take((size_t)n * 16 * sizeof(float));
    float*    uout    = (float*)d_out;

    const int gn  = (n + NB - 1) / NB;       // 391
    const int gn4 = (n * 4 + NB - 1) / NB;   // 1563
    const int gre = (e + CH - 1) / CH;       // 782
    const int gz  = (((nsb > nm) ? nsb : nm) + NB - 1) / NB;

    k_zero<<<gz, NB, 0, stream>>>(sbhist, mask, nsb, nm);
    k_hist<<<512, NB, 0, stream>>>(dst, e, sbhist, nsb);
    k_scan_sb<<<1, NSBP, 0, stream>>>(sbhist, sbbase, bcur, nsb);
    k_reorder<<<gre, RT, 0, stream>>>(src, dst, e, bcur, sedge);
    k_fine_cnt<<<nsb, SBSIZE, 0, stream>>>(sedge, sbbase, cnt, n);
    k_scan1<<<gn, NB, 0, stream>>>(cnt, partial, n);
    k_scan2<<<1, 512, 0, stream>>>(partial, gn);
    k_scan3<<<gn, NB, 0, stream>>>(cnt, partial, rowptr, n);
    k_place<<<nsb, SBSIZE, 0, stream>>>(sedge, sbbase, rowptr, cnt, mask, adj, n);
    k_init_u<<<gn4, NB, 0, stream>>>((const v4f*)x, cnt, (v4f*)uout, n * 4);

    float* cur = uout;   // 12 layers (even) -> result ends in d_out
    float* nxt = uws;
    for (int l = 0; l < 12; ++l) {
        k_layer<<<gn4, NB, 0, stream>>>(rowptr, cnt, adj, (const v4f*)cur, (v4f*)nxt, n);
        float* tp = cur; cur = nxt; nxt = tp;
    }
    k_finish<<<gn4, NB, 0, stream>>>((v4f*)uout, cnt, mask, n * 4);
}